// Round 8
// baseline (1431.246 us; speedup 1.0000x reference)
//
#include <hip/hip_runtime.h>
#include <hip/hip_bf16.h>

#define Hdim 2880
#define Idim 2880
#define NEXP 8
#define NTOK 64
#define TOPK 4
#define NHC 3            // K-chunks for gate/up GEMM (2880/3 = 960)
#define HPC (Hdim/NHC)   // 960
#define JCH 576          // K-chunk for down GEMM (5 per expert)
#define NJC_PER_E 5
#define BCOL 192         // columns per block (2880/192 = 15 tiles)

// ---------------- workspace layout (bytes) ----------------
#define WS_CNT      0            // 8 ints
#define WS_TOKID    256          // 8*64 ints
#define WS_DENSEW   2560         // 64*8 floats
#define WS_MASK     4608         // 64*8 ints
#define WS_PARTGU   8192         // [2][NHC][8][64][Idim] f32 = 35,389,440 B
#define WS_GATED    (8192 + 35389440)            // [8][64][Idim] f32
#define WS_PARTOUT  (8192 + 35389440 + 5898240)  // [40][64][Hdim] f32
#define WS_NEEDED   (8192 + 35389440 + 5898240 + 29491200)  // 70,787,072 B

// ---------------- router: logits, top-4, softmax, token lists ----------------
__global__ __launch_bounds__(64) void router_kernel(
    const float* __restrict__ x, const float* __restrict__ rw,
    const float* __restrict__ rb,
    float* __restrict__ dense_w, int* __restrict__ mask,
    int* __restrict__ tok_id, int* __restrict__ cnt)
{
    const int t = blockIdx.x;
    const int lane = threadIdx.x;
    float lg[NEXP];
#pragma unroll
    for (int e = 0; e < NEXP; ++e) {
        float p = 0.f;
        for (int h = lane; h < Hdim; h += 64)
            p = fmaf(x[t*Hdim + h], rw[e*Hdim + h], p);
#pragma unroll
        for (int m = 32; m; m >>= 1) p += __shfl_xor(p, m);
        lg[e] = p + rb[e];
    }
    if (lane == 0) {
        bool used[NEXP] = {};
        float kv[TOPK]; int ki[TOPK];
#pragma unroll
        for (int k = 0; k < TOPK; ++k) {
            float best = -1e30f; int bi = 0;
#pragma unroll
            for (int e = 0; e < NEXP; ++e)
                if (!used[e] && lg[e] > best) { best = lg[e]; bi = e; }
            used[bi] = true; kv[k] = best; ki[k] = bi;
        }
        const float m = kv[0];
        float ex[TOPK]; float sum = 0.f;
#pragma unroll
        for (int k = 0; k < TOPK; ++k) { ex[k] = expf(kv[k]-m); sum += ex[k]; }
        const float inv = 1.f / sum;
#pragma unroll
        for (int e = 0; e < NEXP; ++e) { dense_w[t*NEXP+e] = 0.f; mask[t*NEXP+e] = 0; }
#pragma unroll
        for (int k = 0; k < TOPK; ++k) {
            const int e = ki[k];
            dense_w[t*NEXP+e] = ex[k]*inv;
            mask[t*NEXP+e] = 1;
            const int slot = atomicAdd(&cnt[e], 1);
            tok_id[e*64 + slot] = t;
        }
    }
}

// ---------------- fused gate/up GEMM, register-tiled 12x4 ----------------
// Thread (tc,ts) = (tid&15, tid>>4) owns cols {cb+tc+16k, k<12} x slots
// {ts*4+j, j<4}. Per K-row: 12 coalesced weight loads (offset-folded),
// ONE ds_read_b128 (4 slots), 48 FMA -> LDS pipe ~50% worst case.
// LDS tile xs[row][slot] double-buffered; next chunk's x prefetched to regs.
__global__ __launch_bounds__(256) void gu_gemm(
    const float* __restrict__ Wg, const float* __restrict__ Wu,
    const float* __restrict__ x,
    const int* __restrict__ tok_id, const int* __restrict__ cnt,
    float* __restrict__ partial)
{
    const int bx = blockIdx.x;             // 0..14
    const int hc = blockIdx.y;             // 0..NHC-1
    const int z  = blockIdx.z;
    const int e  = z & 7;
    const int which = z >> 3;
    const float* __restrict__ W = which ? Wu : Wg;
    const int c = cnt[e];
    const int nch = (c + 15) >> 4;
    if (nch == 0) return;                  // uniform exit

    const int tid = threadIdx.x;
    const int tc = tid & 15;
    const int ts = tid >> 4;               // 0..15
    const bool active = (ts >> 2) < nch;   // wave-uniform

    __shared__ float xs[2][64][64];        // [buf][row][slot]

    float acc[12][4];
#pragma unroll
    for (int k = 0; k < 12; ++k)
#pragma unroll
        for (int j = 0; j < 4; ++j) acc[k][j] = 0.f;

    // staging role: slot s_mine, rows hb0*16..hb0*16+15 (consecutive floats)
    const int s_mine = tid & 63;
    const int hb0    = tid >> 6;           // 0..3
    const float* __restrict__ xrow =
        x + (size_t)tok_id[(e<<6) + s_mine] * Hdim + hc*HPC + hb0*16;

    const int cb = bx * BCOL;
    const float* __restrict__ wq0 =
        W + ((size_t)e*Hdim + (size_t)hc*HPC)*Idim + cb + tc;

    // prologue: stage chunk 0
    float4 r4[4];
#pragma unroll
    for (int q = 0; q < 4; ++q) r4[q] = *(const float4*)(xrow + q*4);
#pragma unroll
    for (int rr = 0; rr < 16; ++rr)
        xs[0][hb0*16 + rr][s_mine] = (&r4[rr>>2].x)[rr&3];
    __syncthreads();

    int cur = 0;
    for (int h0 = 0; h0 < HPC; h0 += 64) {
        const bool more = (h0 + 64 < HPC);
        if (more) {
#pragma unroll
            for (int q = 0; q < 4; ++q)
                r4[q] = *(const float4*)(xrow + h0 + 64 + q*4);
        }
        if (active) {
            const float* __restrict__ wq = wq0 + (size_t)h0 * Idim;
            const float (* __restrict__ xb)[64] = xs[cur];
#pragma unroll 2
            for (int r = 0; r < 64; ++r) {
                float w[12];
#pragma unroll
                for (int k = 0; k < 12; ++k)
                    w[k] = __builtin_nontemporal_load(wq + (size_t)r*Idim + k*16);
                const float4 xv = *(const float4*)&xb[r][ts*4];
#pragma unroll
                for (int k = 0; k < 12; ++k) {
                    acc[k][0] = fmaf(w[k], xv.x, acc[k][0]);
                    acc[k][1] = fmaf(w[k], xv.y, acc[k][1]);
                    acc[k][2] = fmaf(w[k], xv.z, acc[k][2]);
                    acc[k][3] = fmaf(w[k], xv.w, acc[k][3]);
                }
            }
        }
        __syncthreads();
        if (more) {
#pragma unroll
            for (int rr = 0; rr < 16; ++rr)
                xs[cur^1][hb0*16 + rr][s_mine] = (&r4[rr>>2].x)[rr&3];
        }
        __syncthreads();
        cur ^= 1;
    }

    float* __restrict__ P = partial +
        ((((size_t)which*NHC + hc)*NEXP + e) << 6) * Idim + cb + tc;
#pragma unroll
    for (int j = 0; j < 4; ++j) {
        const int s = ts*4 + j;
        if (s < c) {
#pragma unroll
            for (int k = 0; k < 12; ++k)
                P[(size_t)s*Idim + k*16] = acc[k][j];
        }
    }
}

// ---------------- activation + routing weight -> gated ----------------
__global__ __launch_bounds__(256) void act_kernel(
    const float* __restrict__ pgu, const float* __restrict__ bg,
    const float* __restrict__ bu, const float* __restrict__ dense_w,
    const int* __restrict__ tok_id, const int* __restrict__ cnt,
    float* __restrict__ gated)
{
    const int I4 = Idim/4;                       // 720
    const int idx = blockIdx.x*256 + threadIdx.x;
    if (idx >= NEXP*64*I4) return;
    const int i4 = idx % I4;
    const int rest = idx / I4;
    const int s = rest & 63;
    const int e = rest >> 6;

    float4* __restrict__ gout = (float4*)gated + ((size_t)(e*64+s))*I4 + i4;
    const int c = cnt[e];
    if (s >= c) { *gout = make_float4(0.f,0.f,0.f,0.f); return; }
    const int t = tok_id[(e<<6)+s];
    const float w = dense_w[t*NEXP + e];

    const float4* __restrict__ P = (const float4*)pgu;
    const size_t strideHC = (size_t)NEXP*64*I4;
    const size_t off = ((size_t)(e*64+s))*I4 + i4;
    float4 g = make_float4(0,0,0,0), u = make_float4(0,0,0,0);
#pragma unroll
    for (int hcc = 0; hcc < NHC; ++hcc) {
        float4 a = P[(size_t)hcc*strideHC + off];
        g.x += a.x; g.y += a.y; g.z += a.z; g.w += a.w;
        float4 b = P[(size_t)(NHC+hcc)*strideHC + off];
        u.x += b.x; u.y += b.y; u.z += b.z; u.w += b.w;
    }
    const float4 bg4 = ((const float4*)bg)[(size_t)e*I4 + i4];
    const float4 bu4 = ((const float4*)bu)[(size_t)e*I4 + i4];
    g.x += bg4.x; g.y += bg4.y; g.z += bg4.z; g.w += bg4.w;
    u.x += bu4.x; u.y += bu4.y; u.z += bu4.z; u.w += bu4.w;

    float4 r;
#pragma unroll
    for (int q = 0; q < 4; ++q) {
        const float gv = (&g.x)[q], uv = (&u.x)[q];
        const float gc = fminf(gv, 7.0f);
        const float uc = fminf(fmaxf(uv, -7.0f), 7.0f);
        const float sig = 1.0f / (1.0f + expf(-1.702f * gc));
        (&r.x)[q] = (uc + 1.0f) * (gc * sig) * w;
    }
    *gout = r;
}

// ---------------- down GEMM, register-tiled 12x4 ----------------
__global__ __launch_bounds__(256) void down_gemm(
    const float* __restrict__ Wd, const float* __restrict__ gated,
    const int* __restrict__ tok_id, const int* __restrict__ cnt,
    float* __restrict__ partial)
{
    const int bx = blockIdx.x;   // 0..14
    const int jc = blockIdx.y;   // 0..4
    const int e  = blockIdx.z;   // 0..7
    const int c = cnt[e];
    const int nch = (c + 15) >> 4;
    if (nch == 0) return;

    const int tid = threadIdx.x;
    const int tc = tid & 15;
    const int ts = tid >> 4;
    const bool active = (ts >> 2) < nch;

    __shared__ float gs[2][64][64];

    float acc[12][4];
#pragma unroll
    for (int k = 0; k < 12; ++k)
#pragma unroll
        for (int j = 0; j < 4; ++j) acc[k][j] = 0.f;

    const int s_mine = tid & 63;
    const int ib0    = tid >> 6;
    const float* __restrict__ grow =
        gated + ((size_t)((e<<6) + s_mine))*Idim + jc*JCH + ib0*16;

    const int cb = bx * BCOL;
    const float* __restrict__ wq0 =
        Wd + ((size_t)e*Idim + (size_t)jc*JCH)*Hdim + cb + tc;

    float4 r4[4];
#pragma unroll
    for (int q = 0; q < 4; ++q) r4[q] = *(const float4*)(grow + q*4);
#pragma unroll
    for (int rr = 0; rr < 16; ++rr)
        gs[0][ib0*16 + rr][s_mine] = (&r4[rr>>2].x)[rr&3];
    __syncthreads();

    int cur = 0;
    for (int i0 = 0; i0 < JCH; i0 += 64) {
        const bool more = (i0 + 64 < JCH);
        if (more) {
#pragma unroll
            for (int q = 0; q < 4; ++q)
                r4[q] = *(const float4*)(grow + i0 + 64 + q*4);
        }
        if (active) {
            const float* __restrict__ wq = wq0 + (size_t)i0 * Hdim;
            const float (* __restrict__ gb)[64] = gs[cur];
#pragma unroll 2
            for (int r = 0; r < 64; ++r) {
                float w[12];
#pragma unroll
                for (int k = 0; k < 12; ++k)
                    w[k] = __builtin_nontemporal_load(wq + (size_t)r*Hdim + k*16);
                const float4 gv = *(const float4*)&gb[r][ts*4];
#pragma unroll
                for (int k = 0; k < 12; ++k) {
                    acc[k][0] = fmaf(w[k], gv.x, acc[k][0]);
                    acc[k][1] = fmaf(w[k], gv.y, acc[k][1]);
                    acc[k][2] = fmaf(w[k], gv.z, acc[k][2]);
                    acc[k][3] = fmaf(w[k], gv.w, acc[k][3]);
                }
            }
        }
        __syncthreads();
        if (more) {
#pragma unroll
            for (int rr = 0; rr < 16; ++rr)
                gs[cur^1][ib0*16 + rr][s_mine] = (&r4[rr>>2].x)[rr&3];
        }
        __syncthreads();
        cur ^= 1;
    }

    float* __restrict__ Pb = partial +
        (size_t)(e*NJC_PER_E + jc)*NTOK*Hdim + cb + tc;
#pragma unroll
    for (int j = 0; j < 4; ++j) {
        const int s = ts*4 + j;
        if (s < c) {
            const int t = tok_id[(e<<6)+s];
#pragma unroll
            for (int k = 0; k < 12; ++k)
                Pb[(size_t)t*Hdim + k*16] = acc[k][j];
        }
    }
}

// ---------------- final reduce + weighted bd bias ----------------
__global__ __launch_bounds__(256) void reduce_out(
    const float* __restrict__ partial, const int* __restrict__ mask,
    const float* __restrict__ dense_w, const float* __restrict__ bd,
    float* __restrict__ out)
{
    const int H4 = Hdim/4;                      // 720
    const int idx = blockIdx.x*256 + threadIdx.x;
    if (idx >= NTOK*H4) return;
    const int h4 = idx % H4;
    const int t  = idx / H4;

    float4 sum = make_float4(0,0,0,0);
#pragma unroll
    for (int e = 0; e < NEXP; ++e) {
        const float w = dense_w[t*NEXP + e];
        const float4 b = ((const float4*)bd)[(size_t)e*H4 + h4];
        sum.x = fmaf(w, b.x, sum.x); sum.y = fmaf(w, b.y, sum.y);
        sum.z = fmaf(w, b.z, sum.z); sum.w = fmaf(w, b.w, sum.w);
    }
    const float4* __restrict__ P = (const float4*)partial;
#pragma unroll
    for (int e = 0; e < NEXP; ++e) {
        if (mask[t*NEXP + e]) {
#pragma unroll
            for (int q = 0; q < NJC_PER_E; ++q) {
                const float4 a = P[((size_t)(e*NJC_PER_E+q)*NTOK + t)*H4 + h4];
                sum.x += a.x; sum.y += a.y; sum.z += a.z; sum.w += a.w;
            }
        }
    }
    ((float4*)out)[idx] = sum;
}

// ---------------- launch ----------------
extern "C" void kernel_launch(void* const* d_in, const int* in_sizes, int n_in,
                              void* d_out, int out_size, void* d_ws, size_t ws_size,
                              hipStream_t stream)
{
    // Diagnostic guard: if the harness workspace is smaller than our layout,
    // do NOT scribble past it (container crash, no signal). Emit an all-zero
    // output instead -> clean validation failure we can recognize next round.
    if (ws_size < (size_t)WS_NEEDED) {
        hipMemsetAsync(d_out, 0, (size_t)out_size * sizeof(float), stream);
        return;
    }

    const float* x  = (const float*)d_in[0];
    const float* rw = (const float*)d_in[1];
    const float* rb = (const float*)d_in[2];
    const float* Wg = (const float*)d_in[3];
    const float* bg = (const float*)d_in[4];
    const float* Wu = (const float*)d_in[5];
    const float* bu = (const float*)d_in[6];
    const float* Wd = (const float*)d_in[7];
    const float* bd = (const float*)d_in[8];
    float* out = (float*)d_out;

    char* ws = (char*)d_ws;
    int*   cnt     = (int*)(ws + WS_CNT);
    int*   tok_id  = (int*)(ws + WS_TOKID);
    float* dense_w = (float*)(ws + WS_DENSEW);
    int*   mask    = (int*)(ws + WS_MASK);
    float* pgu     = (float*)(ws + WS_PARTGU);
    float* gated   = (float*)(ws + WS_GATED);
    float* pout    = (float*)(ws + WS_PARTOUT);

    // zero cnt + tok_id (tok_id must be valid for ALL 64 staging slots)
    hipMemsetAsync(ws, 0, WS_TOKID + 8*64*sizeof(int), stream);

    router_kernel<<<dim3(NTOK), dim3(64), 0, stream>>>(
        x, rw, rb, dense_w, mask, tok_id, cnt);

    gu_gemm<<<dim3(Hdim/BCOL, NHC, 16), dim3(256), 0, stream>>>(
        Wg, Wu, x, tok_id, cnt, pgu);

    act_kernel<<<dim3((NEXP*64*(Idim/4) + 255)/256), dim3(256), 0, stream>>>(
        pgu, bg, bu, dense_w, tok_id, cnt, gated);

    down_gemm<<<dim3(Hdim/BCOL, NJC_PER_E, NEXP), dim3(256), 0, stream>>>(
        Wd, gated, tok_id, cnt, pout);

    reduce_out<<<dim3((NTOK*(Hdim/4) + 255)/256), dim3(256), 0, stream>>>(
        pout, mask, dense_w, bd, out);
}